// Round 4
// baseline (239.518 us; speedup 1.0000x reference)
//
#include <hip/hip_runtime.h>
#include <hip/hip_bf16.h>

// out[b,s] = cumsum_s( softplus(beta * c[b,s]) / beta ), fp32, B=4096, S=8192.
//
// R4: ONE WAVE PER ROW, NO BARRIERS, register-pipelined groups.
// R1-R3 all landed at ~82 us with VALU 27% and HBM ~50% busy — additive, not
// overlapped: short-lived blocks execute load-burst / barrier(vmcnt-drain) /
// compute / store-burst in phase-correlated convoys. Fix: each 64-lane wave
// owns a full row (8192 floats = 32 lane-coalesced float4 chunks), processed
// as 4 groups of 8 chunks with an explicit 2-buffer register pipeline, so
// group g+1's 8 loads are in flight during group g's softplus+scan+store.
// The only cross-chunk dependency is a scalar carry (one add per chunk, fed
// by independent pipelined wave shuffle-scans). No LDS data, no syncthreads,
// nothing ever forces vmcnt(0). 1024 blocks x 4 waves = 4096 long-lived
// waves = exactly 4 blocks/CU, no dispatch tail.

#define ROW_S   8192
#define BLOCK_T 256
#define CHUNK   64              // float4 per chunk (one per lane)
#define NCH     8               // chunks per group
#define NG      4               // groups per row: 4*8*64*4 = 8192 elems

__device__ __forceinline__ float softplus_step(float c, float beta, float inv_beta) {
    float tb = beta * c;
    float e  = __expf(-fabsf(tb));     // in (0,1], no overflow
    float l  = __logf(1.0f + e);       // log1p(exp(-|t|))
    return (fmaxf(tb, 0.0f) + l) * inv_beta;
}

__global__ __launch_bounds__(BLOCK_T, 4) void softplus_cumsum_kernel(
    const float* __restrict__ c,
    const float* __restrict__ beta_p,
    float* __restrict__ out)
{
    const int lane = threadIdx.x & 63;
    const int row  = blockIdx.x * (BLOCK_T / 64) + (threadIdx.x >> 6);

    const float beta     = beta_p[0];
    const float inv_beta = 1.0f / beta;

    const float4* __restrict__ in4  = (const float4*)c   + (size_t)row * (ROW_S / 4);
    float4*       __restrict__ out4 = (float4*)out       + (size_t)row * (ROW_S / 4);

    // Two register buffers; parity indices are compile-time after full unroll,
    // so there is no rotate-copy for the compiler to exploit.
    float4 v[2][NCH];

    // Prologue: load group 0.
    #pragma unroll
    for (int ch = 0; ch < NCH; ++ch)
        v[0][ch] = in4[ch * CHUNK + lane];

    float carry = 0.0f;

    #pragma unroll
    for (int g = 0; g < NG; ++g) {
        const int cur = g & 1;
        const int nxt = cur ^ 1;

        // Prefetch group g+1 BEFORE any compute on group g (stays in flight
        // across the whole group's softplus+scan+store — no barrier to drain it).
        if (g + 1 < NG) {
            #pragma unroll
            for (int ch = 0; ch < NCH; ++ch)
                v[nxt][ch] = in4[(g + 1) * NCH * CHUNK + ch * CHUNK + lane];
        }

        // 8 chunks: scans are independent (pipeline freely); only the scalar
        // carry add chains across chunks.
        #pragma unroll
        for (int ch = 0; ch < NCH; ++ch) {
            float4 e = v[cur][ch];
            float p0 = softplus_step(e.x, beta, inv_beta);
            float p1 = p0 + softplus_step(e.y, beta, inv_beta);
            float p2 = p1 + softplus_step(e.z, beta, inv_beta);
            float p3 = p2 + softplus_step(e.w, beta, inv_beta);

            // wave-inclusive scan of the per-lane chunk sum p3
            float x = p3;
            #pragma unroll
            for (int d = 1; d < 64; d <<= 1) {
                float y = __shfl_up(x, d, 64);
                if (lane >= d) x += y;
            }
            const float excl = x - p3;             // exclusive over lanes
            const float tot  = __shfl(x, 63, 64);  // wave-uniform chunk total

            const float off = carry + excl;
            float4 o;
            o.x = off + p0;
            o.y = off + p1;
            o.z = off + p2;
            o.w = off + p3;
            out4[g * NCH * CHUNK + ch * CHUNK + lane] = o;

            carry += tot;
        }
    }
}

extern "C" void kernel_launch(void* const* d_in, const int* in_sizes, int n_in,
                              void* d_out, int out_size, void* d_ws, size_t ws_size,
                              hipStream_t stream) {
    const float* c      = (const float*)d_in[0];
    const float* beta_p = (const float*)d_in[1];
    float*       out    = (float*)d_out;

    const int B = in_sizes[0] / ROW_S;                  // 4096 rows
    const int waves_per_block = BLOCK_T / 64;           // 4
    const int nblocks = B / waves_per_block;            // 1024 blocks, exact
    softplus_cumsum_kernel<<<dim3(nblocks), dim3(BLOCK_T), 0, stream>>>(
        c, beta_p, out);
}